// Round 1
// baseline (443.021 us; speedup 1.0000x reference)
//
#include <hip/hip_runtime.h>
#include <hip/hip_bf16.h>

#define NN 100000
#define INDIM 128
#define HID 32
#define BN_EPS 1e-5f

// ---------------------------------------------------------------- detect int64
__global__ void ge_detect(const int* __restrict__ ei, int* __restrict__ flag) {
    // If edge_index is int64 (LE), values < 2^31 => every odd 32-bit word is 0.
    int is64 = 1;
    for (int i = 1; i < 128; i += 2)
        if (ei[i] != 0) { is64 = 0; break; }
    *flag = is64;
}

// ---------------------------------------------------------------- degree histogram
__global__ void ge_degree(const int* __restrict__ ei, const int* __restrict__ flag,
                          unsigned* __restrict__ deg, int E) {
    int e = blockIdx.x * blockDim.x + threadIdx.x;
    if (e >= E) return;
    int is64 = *flag;
    int d = is64 ? ei[2 * (E + e)] : ei[E + e];
    atomicAdd(&deg[d], 1u);
}

// ---------------------------------------------------------------- scan (3 kernels)
__global__ void ge_scan1(const unsigned* __restrict__ deg, unsigned* __restrict__ row_start,
                         unsigned* __restrict__ part, int n) {
    __shared__ unsigned s[1024];
    int i = blockIdx.x * 1024 + threadIdx.x;
    unsigned v = (i < n) ? deg[i] : 0u;
    s[threadIdx.x] = v;
    __syncthreads();
    for (int off = 1; off < 1024; off <<= 1) {
        unsigned t = (threadIdx.x >= off) ? s[threadIdx.x - off] : 0u;
        __syncthreads();
        s[threadIdx.x] += t;
        __syncthreads();
    }
    unsigned incl = s[threadIdx.x];
    if (i < n) row_start[i] = incl - v;          // exclusive within block
    if (threadIdx.x == 1023) part[blockIdx.x] = incl;
}

__global__ void ge_scan2(unsigned* __restrict__ part, int nb) {
    __shared__ unsigned s[128];
    unsigned v = (threadIdx.x < nb) ? part[threadIdx.x] : 0u;
    s[threadIdx.x] = v;
    __syncthreads();
    for (int off = 1; off < 128; off <<= 1) {
        unsigned t = (threadIdx.x >= off) ? s[threadIdx.x - off] : 0u;
        __syncthreads();
        s[threadIdx.x] += t;
        __syncthreads();
    }
    if (threadIdx.x < nb) part[threadIdx.x] = s[threadIdx.x] - v;   // exclusive
}

__global__ void ge_scan3(unsigned* __restrict__ row_start, const unsigned* __restrict__ part,
                         unsigned* __restrict__ wptr, const unsigned* __restrict__ deg,
                         float* __restrict__ dinv, int n) {
    int i = blockIdx.x * blockDim.x + threadIdx.x;
    if (i >= n) return;
    unsigned r = row_start[i] + part[i >> 10];
    row_start[i] = r;
    wptr[i] = r;
    dinv[i] = rsqrtf((float)(deg[i] + 1u));      // +1 self loop
}

// ---------------------------------------------------------------- CSR fill
__global__ void ge_fill(const int* __restrict__ ei, const int* __restrict__ flag,
                        unsigned* __restrict__ wptr, unsigned* __restrict__ col, int E) {
    int e = blockIdx.x * blockDim.x + threadIdx.x;
    if (e >= E) return;
    int is64 = *flag;
    int s = is64 ? ei[2 * e] : ei[e];
    int d = is64 ? ei[2 * (E + e)] : ei[E + e];
    unsigned slot = atomicAdd(&wptr[d], 1u);
    col[slot] = (unsigned)s;
}

// ---------------------------------------------------------------- g1 = (x @ W1) * dinv
__global__ __launch_bounds__(256) void ge_gemm1(const float* __restrict__ x,
                                                const float* __restrict__ W1,
                                                const float* __restrict__ dinv,
                                                float* __restrict__ g1, int n) {
    int node = blockIdx.x * blockDim.x + threadIdx.x;
    if (node >= n) return;
    float acc[HID];
#pragma unroll
    for (int c = 0; c < HID; c++) acc[c] = 0.f;
    const float4* xr = (const float4*)(x + (size_t)node * INDIM);
    for (int k4 = 0; k4 < INDIM / 4; k4++) {
        float4 xv = xr[k4];
        const float* w = W1 + (size_t)k4 * 4 * HID;
#pragma unroll
        for (int kk = 0; kk < 4; kk++) {
            float xk = (&xv.x)[kk];
#pragma unroll
            for (int c = 0; c < HID; c++) acc[c] = fmaf(xk, w[kk * HID + c], acc[c]);
        }
    }
    float dv = dinv[node];
    float4* out = (float4*)(g1 + (size_t)node * HID);
#pragma unroll
    for (int c4 = 0; c4 < HID / 4; c4++) {
        float4 o;
        o.x = acc[c4 * 4 + 0] * dv;
        o.y = acc[c4 * 4 + 1] * dv;
        o.z = acc[c4 * 4 + 2] * dv;
        o.w = acc[c4 * 4 + 3] * dv;
        out[c4] = o;
    }
}

// ---------------------------------------------------------------- gather: out = dinv*(sum g[src] + g[i]) + bias
__global__ __launch_bounds__(256) void ge_gather(const float* __restrict__ g,
                                                 const unsigned* __restrict__ row_start,
                                                 const unsigned* __restrict__ deg,
                                                 const unsigned* __restrict__ col,
                                                 const float* __restrict__ dinv,
                                                 const float* __restrict__ bias,
                                                 float* __restrict__ out, int n) {
    int idx = blockIdx.x * blockDim.x + threadIdx.x;
    int node = idx >> 5;
    int c = idx & 31;
    if (node >= n) return;
    unsigned start = row_start[node];
    unsigned len = deg[node];
    float acc = g[(size_t)node * HID + c];       // self loop term
    unsigned j = 0;
    for (; j + 4 <= len; j += 4) {
        unsigned c0 = col[start + j + 0];
        unsigned c1 = col[start + j + 1];
        unsigned c2 = col[start + j + 2];
        unsigned c3 = col[start + j + 3];
        float v0 = g[(size_t)c0 * HID + c];
        float v1 = g[(size_t)c1 * HID + c];
        float v2 = g[(size_t)c2 * HID + c];
        float v3 = g[(size_t)c3 * HID + c];
        acc += v0 + v1 + v2 + v3;
    }
    for (; j < len; j++) acc += g[(size_t)col[start + j] * HID + c];
    out[(size_t)node * HID + c] = dinv[node] * acc + bias[c];
}

// ---------------------------------------------------------------- BN stats
__global__ __launch_bounds__(256) void ge_bnstats(const float* __restrict__ h1,
                                                  float* __restrict__ bnsum,
                                                  float* __restrict__ bnsumsq, int n) {
    int t = threadIdx.x;
    int c = t & 31;
    int rg = t >> 5;                              // 0..7
    float s = 0.f, q = 0.f;
    for (int r = blockIdx.x * 8 + rg; r < n; r += gridDim.x * 8) {
        float v = h1[(size_t)r * HID + c];
        s += v;
        q += v * v;
    }
    __shared__ float Ls[256], Lq[256];
    Ls[t] = s; Lq[t] = q;
    __syncthreads();
    for (int off = 128; off >= 32; off >>= 1) {
        if (t < off) { Ls[t] += Ls[t + off]; Lq[t] += Lq[t + off]; }
        __syncthreads();
    }
    if (t < 32) {
        atomicAdd(&bnsum[t], Ls[t]);
        atomicAdd(&bnsumsq[t], Lq[t]);
    }
}

__global__ void ge_bnfinal(const float* __restrict__ bnsum, const float* __restrict__ bnsumsq,
                           const float* __restrict__ gamma, const float* __restrict__ beta,
                           float* __restrict__ ab, int n) {
    int c = threadIdx.x;
    if (c >= HID) return;
    float inv_n = 1.f / (float)n;
    float mean = bnsum[c] * inv_n;
    float var = fmaxf(bnsumsq[c] * inv_n - mean * mean, 0.f);
    float inv = rsqrtf(var + BN_EPS);
    float a = gamma[c] * inv;
    ab[c] = a;
    ab[HID + c] = beta[c] - mean * a;
}

// ---------------------------------------------------------------- g2 = (relu(a*h1+b) @ W2) * dinv
__global__ __launch_bounds__(256) void ge_gemm2(const float* __restrict__ h1,
                                                const float* __restrict__ W2,
                                                const float* __restrict__ ab,
                                                const float* __restrict__ dinv,
                                                float* __restrict__ g2, int n) {
    int node = blockIdx.x * blockDim.x + threadIdx.x;
    if (node >= n) return;
    float p[HID];
    const float4* hr = (const float4*)(h1 + (size_t)node * HID);
#pragma unroll
    for (int k4 = 0; k4 < HID / 4; k4++) {
        float4 v = hr[k4];
#pragma unroll
        for (int kk = 0; kk < 4; kk++) {
            int k = k4 * 4 + kk;
            p[k] = fmaxf(fmaf(ab[k], (&v.x)[kk], ab[HID + k]), 0.f);
        }
    }
    float acc[HID];
#pragma unroll
    for (int c = 0; c < HID; c++) acc[c] = 0.f;
#pragma unroll
    for (int k = 0; k < HID; k++) {
        float pk = p[k];
        const float* w = W2 + (size_t)k * HID;
#pragma unroll
        for (int c = 0; c < HID; c++) acc[c] = fmaf(pk, w[c], acc[c]);
    }
    float dv = dinv[node];
    float4* out = (float4*)(g2 + (size_t)node * HID);
#pragma unroll
    for (int c4 = 0; c4 < HID / 4; c4++) {
        float4 o;
        o.x = acc[c4 * 4 + 0] * dv;
        o.y = acc[c4 * 4 + 1] * dv;
        o.z = acc[c4 * 4 + 2] * dv;
        o.w = acc[c4 * 4 + 3] * dv;
        out[c4] = o;
    }
}

// ================================================================ launch
extern "C" void kernel_launch(void* const* d_in, const int* in_sizes, int n_in,
                              void* d_out, int out_size, void* d_ws, size_t ws_size,
                              hipStream_t stream) {
    const float* x     = (const float*)d_in[0];
    const int*   ei    = (const int*)d_in[1];
    const float* W1    = (const float*)d_in[2];
    const float* b1    = (const float*)d_in[3];
    const float* gamma = (const float*)d_in[4];
    const float* beta  = (const float*)d_in[5];
    const float* W2    = (const float*)d_in[6];
    const float* b2    = (const float*)d_in[7];
    float* outp = (float*)d_out;

    const int n = in_sizes[0] / INDIM;       // 100000
    const int E = in_sizes[1] / 2;           // 1600000 (element count, dtype-agnostic)

    // ---- workspace carve-up (256B aligned) ----
    char* w = (char*)d_ws;
    size_t off = 0;
    auto nxt = [&](size_t b) -> void* {
        void* p = w + off;
        off += (b + 255) & ~(size_t)255;
        return p;
    };
    unsigned* deg     = (unsigned*)nxt((size_t)n * 4);
    float*    bnsum   = (float*)nxt(HID * 4);
    float*    bnsumsq = (float*)nxt(HID * 4);
    unsigned* part    = (unsigned*)nxt(256 * 4);
    size_t zero_end = off;                    // everything above must start at 0
    int*      flag    = (int*)nxt(16);
    float*    dinv    = (float*)nxt((size_t)n * 4);
    unsigned* rowst   = (unsigned*)nxt((size_t)n * 4);
    unsigned* wptr    = (unsigned*)nxt((size_t)n * 4);
    float*    ab      = (float*)nxt(2 * HID * 4);
    unsigned* colx    = (unsigned*)nxt((size_t)E * 4);
    float*    g1      = (float*)nxt((size_t)n * HID * 4);
    float*    h1      = (float*)nxt((size_t)n * HID * 4);
    float*    g2      = g1;                   // g1 dead after first gather

    hipMemsetAsync(d_ws, 0, zero_end, stream);

    ge_detect<<<1, 1, 0, stream>>>(ei, flag);

    int ebl = (E + 255) / 256;
    ge_degree<<<ebl, 256, 0, stream>>>(ei, flag, deg, E);

    int nb = (n + 1023) / 1024;               // 98 <= 128
    ge_scan1<<<nb, 1024, 0, stream>>>(deg, rowst, part, n);
    ge_scan2<<<1, 128, 0, stream>>>(part, nb);
    ge_scan3<<<(n + 255) / 256, 256, 0, stream>>>(rowst, part, wptr, deg, dinv, n);

    ge_fill<<<ebl, 256, 0, stream>>>(ei, flag, wptr, colx, E);

    ge_gemm1<<<(n + 255) / 256, 256, 0, stream>>>(x, W1, dinv, g1, n);

    int gbl = ((n * 32) + 255) / 256;
    ge_gather<<<gbl, 256, 0, stream>>>(g1, rowst, deg, colx, dinv, b1, h1, n);

    ge_bnstats<<<1024, 256, 0, stream>>>(h1, bnsum, bnsumsq, n);
    ge_bnfinal<<<1, 64, 0, stream>>>(bnsum, bnsumsq, gamma, beta, ab, n);

    ge_gemm2<<<(n + 255) / 256, 256, 0, stream>>>(h1, W2, ab, dinv, g2, n);

    ge_gather<<<gbl, 256, 0, stream>>>(g2, rowst, deg, colx, dinv, b2, outp, n);
}

// Round 3
// 302.066 us; speedup vs baseline: 1.4666x; 1.4666x over previous
//
#include <hip/hip_runtime.h>
#include <hip/hip_bf16.h>

#define INDIM 128
#define HID 32
#define BN_EPS 1e-5f
#define BSH 8                  // 256 nodes per bucket
#define MAXB 512               // max buckets (n <= 131072)
#define PCHUNK 4096            // edges per partition block

// ---------------------------------------------------------------- detect int64
__global__ void ge_detect(const int* __restrict__ ei, int* __restrict__ flag) {
    int is64 = 1;
    for (int i = 1; i < 128; i += 2)
        if (ei[i] != 0) { is64 = 0; break; }
    *flag = is64;
}

// ---------------------------------------------------------------- bucket histogram
__global__ __launch_bounds__(256) void ge_bhist(const int* __restrict__ ei,
                                                const int* __restrict__ flag,
                                                unsigned* __restrict__ bcnt, int E, int nb) {
    __shared__ unsigned h[MAXB];
    int t = threadIdx.x;
    h[t] = 0; h[t + 256] = 0;
    __syncthreads();
    int is64 = *flag;
    int stride = gridDim.x * 256;
    if (is64) {
        const unsigned long long* p = (const unsigned long long*)ei;
        for (int e = blockIdx.x * 256 + t; e < E; e += stride)
            atomicAdd(&h[((unsigned)p[E + e]) >> BSH], 1u);
    } else {
        for (int e = blockIdx.x * 256 + t; e < E; e += stride)
            atomicAdd(&h[((unsigned)ei[E + e]) >> BSH], 1u);
    }
    __syncthreads();
    for (int b = t; b < nb; b += 256)
        if (h[b]) atomicAdd(&bcnt[b], h[b]);
}

// ---------------------------------------------------------------- bucket scan (1 block)
__global__ void ge_bscan(const unsigned* __restrict__ bcnt, unsigned* __restrict__ bstart,
                         unsigned* __restrict__ bwptr, int nb, int E) {
    __shared__ unsigned s[MAXB];
    int t = threadIdx.x;                       // 512 threads
    unsigned v = (t < nb) ? bcnt[t] : 0u;
    s[t] = v;
    __syncthreads();
    for (int off = 1; off < MAXB; off <<= 1) {
        unsigned u = (t >= off) ? s[t - off] : 0u;
        __syncthreads();
        s[t] += u;
        __syncthreads();
    }
    if (t < nb) { unsigned ex = s[t] - v; bstart[t] = ex; bwptr[t] = ex; }
    if (t == 0) bstart[nb] = (unsigned)E;
}

// ---------------------------------------------------------------- partition edges into buckets
__global__ __launch_bounds__(256) void ge_bpart(const int* __restrict__ ei,
                                                const int* __restrict__ flag,
                                                unsigned* __restrict__ bwptr,
                                                uint2* __restrict__ ebuf, int E, int nb) {
    __shared__ uint2 es[PCHUNK];
    __shared__ unsigned cnt[MAXB];
    __shared__ unsigned base[MAXB];
    int t = threadIdx.x;
    int start = blockIdx.x * PCHUNK;
    int len = min(PCHUNK, E - start);
    cnt[t] = 0; cnt[t + 256] = 0;
    __syncthreads();
    int is64 = *flag;
    if (is64) {
        const unsigned long long* p = (const unsigned long long*)ei;
        for (int i = t; i < len; i += 256) {
            unsigned s = (unsigned)p[start + i];
            unsigned d = (unsigned)p[E + start + i];
            es[i] = make_uint2(s, d);
            atomicAdd(&cnt[d >> BSH], 1u);
        }
    } else {
        for (int i = t; i < len; i += 256) {
            unsigned s = (unsigned)ei[start + i];
            unsigned d = (unsigned)ei[E + start + i];
            es[i] = make_uint2(s, d);
            atomicAdd(&cnt[d >> BSH], 1u);
        }
    }
    __syncthreads();
    for (int b = t; b < nb; b += 256) {
        unsigned c = cnt[b];
        base[b] = c ? atomicAdd(&bwptr[b], c) : 0u;
        cnt[b] = 0;                            // becomes cursor
    }
    __syncthreads();
    for (int i = t; i < len; i += 256) {
        uint2 e = es[i];
        unsigned b = e.y >> BSH;
        unsigned pos = base[b] + atomicAdd(&cnt[b], 1u);
        ebuf[pos] = e;
    }
}

// ---------------------------------------------------------------- per-bucket CSR build
__global__ __launch_bounds__(256) void ge_bcsr(const uint2* __restrict__ ebuf,
                                               const unsigned* __restrict__ bstart,
                                               unsigned* __restrict__ rowst,
                                               unsigned* __restrict__ deg,
                                               float* __restrict__ dinv,
                                               unsigned* __restrict__ col, int n) {
    __shared__ unsigned cnt[256];
    __shared__ unsigned pos[256];
    int b = blockIdx.x;
    int t = threadIdx.x;
    unsigned bs = bstart[b], be = bstart[b + 1];
    cnt[t] = 0;
    __syncthreads();
    for (unsigned i = bs + t; i < be; i += 256)
        atomicAdd(&cnt[ebuf[i].y & 255u], 1u);
    __syncthreads();
    unsigned v = cnt[t];
    pos[t] = v;
    __syncthreads();
    for (int off = 1; off < 256; off <<= 1) {
        unsigned u = (t >= off) ? pos[t - off] : 0u;
        __syncthreads();
        pos[t] += u;
        __syncthreads();
    }
    unsigned ex = pos[t] - v;                  // exclusive local scan
    int node = (b << BSH) + t;
    if (node < n) {
        rowst[node] = bs + ex;
        deg[node] = v;
        dinv[node] = rsqrtf((float)(v + 1u));  // +1 self loop
    }
    __syncthreads();
    pos[t] = ex;
    cnt[t] = 0;                                // cursor
    __syncthreads();
    for (unsigned i = bs + t; i < be; i += 256) {
        uint2 e = ebuf[i];
        unsigned d = e.y & 255u;
        unsigned o = atomicAdd(&cnt[d], 1u);
        col[bs + pos[d] + o] = e.x;
    }
}

// ---------------------------------------------------------------- g1 = (x @ W1) * dinv
__global__ __launch_bounds__(256) void ge_gemm1(const float* __restrict__ x,
                                                const float* __restrict__ W1,
                                                const float* __restrict__ dinv,
                                                float* __restrict__ g1, int n) {
    int node = blockIdx.x * blockDim.x + threadIdx.x;
    if (node >= n) return;
    float acc[HID];
#pragma unroll
    for (int c = 0; c < HID; c++) acc[c] = 0.f;
    const float4* xr = (const float4*)(x + (size_t)node * INDIM);
    for (int k4 = 0; k4 < INDIM / 4; k4++) {
        float4 xv = xr[k4];
        const float* w = W1 + (size_t)k4 * 4 * HID;
#pragma unroll
        for (int kk = 0; kk < 4; kk++) {
            float xk = (&xv.x)[kk];
#pragma unroll
            for (int c = 0; c < HID; c++) acc[c] = fmaf(xk, w[kk * HID + c], acc[c]);
        }
    }
    float dv = dinv[node];
    float4* out = (float4*)(g1 + (size_t)node * HID);
#pragma unroll
    for (int c4 = 0; c4 < HID / 4; c4++) {
        float4 o;
        o.x = acc[c4 * 4 + 0] * dv;
        o.y = acc[c4 * 4 + 1] * dv;
        o.z = acc[c4 * 4 + 2] * dv;
        o.w = acc[c4 * 4 + 3] * dv;
        out[c4] = o;
    }
}

// ---------------------------------------------------------------- gather: out = dinv*(sum g[src] + g[i]) + bias
__global__ __launch_bounds__(256) void ge_gather(const float* __restrict__ g,
                                                 const unsigned* __restrict__ row_start,
                                                 const unsigned* __restrict__ deg,
                                                 const unsigned* __restrict__ col,
                                                 const float* __restrict__ dinv,
                                                 const float* __restrict__ bias,
                                                 float* __restrict__ out, int n) {
    int idx = blockIdx.x * blockDim.x + threadIdx.x;
    int node = idx >> 5;
    int c = idx & 31;
    if (node >= n) return;
    unsigned start = row_start[node];
    unsigned len = deg[node];
    float acc = g[(size_t)node * HID + c];     // self loop term
    unsigned j = 0;
    for (; j + 4 <= len; j += 4) {
        unsigned c0 = col[start + j + 0];
        unsigned c1 = col[start + j + 1];
        unsigned c2 = col[start + j + 2];
        unsigned c3 = col[start + j + 3];
        float v0 = g[(size_t)c0 * HID + c];
        float v1 = g[(size_t)c1 * HID + c];
        float v2 = g[(size_t)c2 * HID + c];
        float v3 = g[(size_t)c3 * HID + c];
        acc += v0 + v1 + v2 + v3;
    }
    for (; j < len; j++) acc += g[(size_t)col[start + j] * HID + c];
    out[(size_t)node * HID + c] = dinv[node] * acc + bias[c];
}

// ---------------------------------------------------------------- BN stats
__global__ __launch_bounds__(256) void ge_bnstats(const float* __restrict__ h1,
                                                  float* __restrict__ bnsum,
                                                  float* __restrict__ bnsumsq, int n) {
    int t = threadIdx.x;
    int c = t & 31;
    int rg = t >> 5;
    float s = 0.f, q = 0.f;
    for (int r = blockIdx.x * 8 + rg; r < n; r += gridDim.x * 8) {
        float v = h1[(size_t)r * HID + c];
        s += v;
        q += v * v;
    }
    __shared__ float Ls[256], Lq[256];
    Ls[t] = s; Lq[t] = q;
    __syncthreads();
    for (int off = 128; off >= 32; off >>= 1) {
        if (t < off) { Ls[t] += Ls[t + off]; Lq[t] += Lq[t + off]; }
        __syncthreads();
    }
    if (t < 32) {
        atomicAdd(&bnsum[t], Ls[t]);
        atomicAdd(&bnsumsq[t], Lq[t]);
    }
}

__global__ void ge_bnfinal(const float* __restrict__ bnsum, const float* __restrict__ bnsumsq,
                           const float* __restrict__ gamma, const float* __restrict__ beta,
                           float* __restrict__ ab, int n) {
    int c = threadIdx.x;
    if (c >= HID) return;
    float inv_n = 1.f / (float)n;
    float mean = bnsum[c] * inv_n;
    float var = fmaxf(bnsumsq[c] * inv_n - mean * mean, 0.f);
    float inv = rsqrtf(var + BN_EPS);
    float a = gamma[c] * inv;
    ab[c] = a;
    ab[HID + c] = beta[c] - mean * a;
}

// ---------------------------------------------------------------- g2 = (relu(a*h1+b) @ W2) * dinv
__global__ __launch_bounds__(256) void ge_gemm2(const float* __restrict__ h1,
                                                const float* __restrict__ W2,
                                                const float* __restrict__ ab,
                                                const float* __restrict__ dinv,
                                                float* __restrict__ g2, int n) {
    int node = blockIdx.x * blockDim.x + threadIdx.x;
    if (node >= n) return;
    float p[HID];
    const float4* hr = (const float4*)(h1 + (size_t)node * HID);
#pragma unroll
    for (int k4 = 0; k4 < HID / 4; k4++) {
        float4 v = hr[k4];
#pragma unroll
        for (int kk = 0; kk < 4; kk++) {
            int k = k4 * 4 + kk;
            p[k] = fmaxf(fmaf(ab[k], (&v.x)[kk], ab[HID + k]), 0.f);
        }
    }
    float acc[HID];
#pragma unroll
    for (int c = 0; c < HID; c++) acc[c] = 0.f;
#pragma unroll
    for (int k = 0; k < HID; k++) {
        float pk = p[k];
        const float* w = W2 + (size_t)k * HID;
#pragma unroll
        for (int c = 0; c < HID; c++) acc[c] = fmaf(pk, w[c], acc[c]);
    }
    float dv = dinv[node];
    float4* out = (float4*)(g2 + (size_t)node * HID);
#pragma unroll
    for (int c4 = 0; c4 < HID / 4; c4++) {
        float4 o;
        o.x = acc[c4 * 4 + 0] * dv;
        o.y = acc[c4 * 4 + 1] * dv;
        o.z = acc[c4 * 4 + 2] * dv;
        o.w = acc[c4 * 4 + 3] * dv;
        out[c4] = o;
    }
}

// ================================================================ launch
extern "C" void kernel_launch(void* const* d_in, const int* in_sizes, int n_in,
                              void* d_out, int out_size, void* d_ws, size_t ws_size,
                              hipStream_t stream) {
    const float* x     = (const float*)d_in[0];
    const int*   ei    = (const int*)d_in[1];
    const float* W1    = (const float*)d_in[2];
    const float* b1    = (const float*)d_in[3];
    const float* gamma = (const float*)d_in[4];
    const float* beta  = (const float*)d_in[5];
    const float* W2    = (const float*)d_in[6];
    const float* b2    = (const float*)d_in[7];
    float* outp = (float*)d_out;

    const int n = in_sizes[0] / INDIM;        // 100000
    const int E = in_sizes[1] / 2;            // 1600000
    const int nb = (n + 255) >> 8;            // 391 buckets

    // ---- workspace carve-up (256B aligned) ----
    char* w = (char*)d_ws;
    size_t off = 0;
    auto nxt = [&](size_t b) -> void* {
        void* p = w + off;
        off += (b + 255) & ~(size_t)255;
        return p;
    };
    unsigned* bcnt    = (unsigned*)nxt(MAXB * 4);
    float*    bnsum   = (float*)nxt(HID * 4);
    float*    bnsumsq = (float*)nxt(HID * 4);
    size_t zero_end = off;                    // everything above starts at 0
    int*      flag    = (int*)nxt(16);
    unsigned* bstart  = (unsigned*)nxt((MAXB + 1) * 4);
    unsigned* bwptr   = (unsigned*)nxt(MAXB * 4);
    unsigned* deg     = (unsigned*)nxt((size_t)n * 4);
    unsigned* rowst   = (unsigned*)nxt((size_t)n * 4);
    float*    dinv    = (float*)nxt((size_t)n * 4);
    float*    ab      = (float*)nxt(2 * HID * 4);
    unsigned* colx    = (unsigned*)nxt((size_t)E * 4);
    float*    g1      = (float*)nxt((size_t)n * HID * 4);
    float*    h1      = (float*)nxt((size_t)n * HID * 4);
    float*    g2      = g1;                   // g1 dead after first gather
    uint2*    ebuf    = (uint2*)d_out;        // E*8B == out bytes; dead before last gather

    hipMemsetAsync(d_ws, 0, zero_end, stream);

    ge_detect<<<1, 1, 0, stream>>>(ei, flag);

    ge_bhist<<<512, 256, 0, stream>>>(ei, flag, bcnt, E, nb);
    ge_bscan<<<1, MAXB, 0, stream>>>(bcnt, bstart, bwptr, nb, E);
    ge_bpart<<<(E + PCHUNK - 1) / PCHUNK, 256, 0, stream>>>(ei, flag, bwptr, ebuf, E, nb);
    ge_bcsr<<<nb, 256, 0, stream>>>(ebuf, bstart, rowst, deg, dinv, colx, n);

    ge_gemm1<<<(n + 255) / 256, 256, 0, stream>>>(x, W1, dinv, g1, n);

    int gbl = ((n * 32) + 255) / 256;
    ge_gather<<<gbl, 256, 0, stream>>>(g1, rowst, deg, colx, dinv, b1, h1, n);

    ge_bnstats<<<1024, 256, 0, stream>>>(h1, bnsum, bnsumsq, n);
    ge_bnfinal<<<1, 64, 0, stream>>>(bnsum, bnsumsq, gamma, beta, ab, n);

    ge_gemm2<<<(n + 255) / 256, 256, 0, stream>>>(h1, W2, ab, dinv, g2, n);

    ge_gather<<<gbl, 256, 0, stream>>>(g2, rowst, deg, colx, dinv, b2, outp, n);
}

// Round 5
// 275.111 us; speedup vs baseline: 1.6103x; 1.0980x over previous
//
#include <hip/hip_runtime.h>
#include <hip/hip_bf16.h>

#define INDIM 128
#define HID 32
#define HID2 16                // channel pairs (bf16x2 per u32)
#define BN_EPS 1e-5f
#define BSH 8                  // 256 nodes per bucket
#define MAXB 512               // max buckets (n <= 131072)
#define PCHUNK 4096            // edges per partition block
#define BNP 64                 // BN partial spread

// ---- bf16 pack/unpack (RNE pack; exact unpack) ----
static __device__ __forceinline__ unsigned pk2bf(float lo, float hi) {
    unsigned a = __float_as_uint(lo);
    unsigned b = __float_as_uint(hi);
    a = (a + 0x7fffu + ((a >> 16) & 1u)) >> 16;
    b = (b + 0x7fffu + ((b >> 16) & 1u)) & 0xffff0000u;
    return a | b;
}
static __device__ __forceinline__ float bflo(unsigned u) { return __uint_as_float(u << 16); }
static __device__ __forceinline__ float bfhi(unsigned u) { return __uint_as_float(u & 0xffff0000u); }

// ---- per-block int64 layout detection (is64 iff ALL 64 odd words zero) ----
static __device__ __forceinline__ int detect_is64(const int* __restrict__ ei, int t) {
    __shared__ int sh;
    if (t == 0) sh = 1;
    __syncthreads();
    if (t < 64 && ei[2 * t + 1] != 0) sh = 0;   // benign race, same value
    __syncthreads();
    return sh;
}

// ---------------------------------------------------------------- bucket histogram
__global__ __launch_bounds__(256) void ge_bhist(const int* __restrict__ ei,
                                                unsigned* __restrict__ bcnt, int E, int nb) {
    int t = threadIdx.x;
    int is64 = detect_is64(ei, t);
    __shared__ unsigned h[MAXB];
    h[t] = 0; h[t + 256] = 0;
    __syncthreads();
    int stride = gridDim.x * 256;
    if (is64) {
        const unsigned long long* p = (const unsigned long long*)ei;
        for (int e = blockIdx.x * 256 + t; e < E; e += stride)
            atomicAdd(&h[((unsigned)p[E + e]) >> BSH], 1u);
    } else {
        for (int e = blockIdx.x * 256 + t; e < E; e += stride)
            atomicAdd(&h[((unsigned)ei[E + e]) >> BSH], 1u);
    }
    __syncthreads();
    for (int b = t; b < nb; b += 256)
        if (h[b]) atomicAdd(&bcnt[b], h[b]);
}

// ---------------------------------------------------------------- bucket scan (1 block)
__global__ void ge_bscan(const unsigned* __restrict__ bcnt, unsigned* __restrict__ bstart,
                         unsigned* __restrict__ bwptr, int nb, int E) {
    __shared__ unsigned s[MAXB];
    int t = threadIdx.x;                       // 512 threads
    unsigned v = (t < nb) ? bcnt[t] : 0u;
    s[t] = v;
    __syncthreads();
    for (int off = 1; off < MAXB; off <<= 1) {
        unsigned u = (t >= off) ? s[t - off] : 0u;
        __syncthreads();
        s[t] += u;
        __syncthreads();
    }
    if (t < nb) { unsigned ex = s[t] - v; bstart[t] = ex; bwptr[t] = ex; }
    if (t == 0) bstart[nb] = (unsigned)E;
}

// ---------------------------------------------------------------- partition edges into buckets
__global__ __launch_bounds__(256) void ge_bpart(const int* __restrict__ ei,
                                                unsigned* __restrict__ bwptr,
                                                uint2* __restrict__ ebuf, int E, int nb) {
    int t = threadIdx.x;
    int is64 = detect_is64(ei, t);
    __shared__ uint2 es[PCHUNK];
    __shared__ unsigned cnt[MAXB];
    __shared__ unsigned base[MAXB];
    int start = blockIdx.x * PCHUNK;
    int len = min(PCHUNK, E - start);
    cnt[t] = 0; cnt[t + 256] = 0;
    __syncthreads();
    if (is64) {
        const unsigned long long* p = (const unsigned long long*)ei;
        for (int i = t; i < len; i += 256) {
            unsigned s = (unsigned)p[start + i];
            unsigned d = (unsigned)p[E + start + i];
            es[i] = make_uint2(s, d);
            atomicAdd(&cnt[d >> BSH], 1u);
        }
    } else {
        for (int i = t; i < len; i += 256) {
            unsigned s = (unsigned)ei[start + i];
            unsigned d = (unsigned)ei[E + start + i];
            es[i] = make_uint2(s, d);
            atomicAdd(&cnt[d >> BSH], 1u);
        }
    }
    __syncthreads();
    for (int b = t; b < nb; b += 256) {
        unsigned c = cnt[b];
        base[b] = c ? atomicAdd(&bwptr[b], c) : 0u;
        cnt[b] = 0;                            // becomes cursor
    }
    __syncthreads();
    for (int i = t; i < len; i += 256) {
        uint2 e = es[i];
        unsigned b = e.y >> BSH;
        unsigned pos = base[b] + atomicAdd(&cnt[b], 1u);
        ebuf[pos] = e;
    }
}

// ---------------------------------------------------------------- per-bucket CSR build
__global__ __launch_bounds__(256) void ge_bcsr(const uint2* __restrict__ ebuf,
                                               const unsigned* __restrict__ bstart,
                                               unsigned* __restrict__ rowst,
                                               unsigned* __restrict__ deg,
                                               float* __restrict__ dinv,
                                               unsigned* __restrict__ col, int n) {
    __shared__ unsigned cnt[256];
    __shared__ unsigned pos[256];
    int b = blockIdx.x;
    int t = threadIdx.x;
    unsigned bs = bstart[b], be = bstart[b + 1];
    cnt[t] = 0;
    __syncthreads();
    for (unsigned i = bs + t; i < be; i += 256)
        atomicAdd(&cnt[ebuf[i].y & 255u], 1u);
    __syncthreads();
    unsigned v = cnt[t];
    pos[t] = v;
    __syncthreads();
    for (int off = 1; off < 256; off <<= 1) {
        unsigned u = (t >= off) ? pos[t - off] : 0u;
        __syncthreads();
        pos[t] += u;
        __syncthreads();
    }
    unsigned ex = pos[t] - v;                  // exclusive local scan
    int node = (b << BSH) + t;
    if (node < n) {
        rowst[node] = bs + ex;
        deg[node] = v;
        dinv[node] = rsqrtf((float)(v + 1u));  // +1 self loop
    }
    __syncthreads();
    pos[t] = ex;
    cnt[t] = 0;                                // cursor
    __syncthreads();
    for (unsigned i = bs + t; i < be; i += 256) {
        uint2 e = ebuf[i];
        unsigned d = e.y & 255u;
        unsigned o = atomicAdd(&cnt[d], 1u);
        col[bs + pos[d] + o] = e.x;
    }
}

// ---------------------------------------------------------------- g1 = bf16((x @ W1) * dinv)
__global__ __launch_bounds__(256) void ge_gemm1(const float* __restrict__ x,
                                                const float* __restrict__ W1,
                                                const float* __restrict__ dinv,
                                                unsigned* __restrict__ g1, int n) {
    int node = blockIdx.x * blockDim.x + threadIdx.x;
    if (node >= n) return;
    float acc[HID];
#pragma unroll
    for (int c = 0; c < HID; c++) acc[c] = 0.f;
    const float4* xr = (const float4*)(x + (size_t)node * INDIM);
#pragma unroll 4
    for (int k4 = 0; k4 < INDIM / 4; k4++) {
        float4 xv = xr[k4];
        const float* w = W1 + (size_t)k4 * 4 * HID;
#pragma unroll
        for (int kk = 0; kk < 4; kk++) {
            float xk = (&xv.x)[kk];
#pragma unroll
            for (int c = 0; c < HID; c++) acc[c] = fmaf(xk, w[kk * HID + c], acc[c]);
        }
    }
    float dv = dinv[node];
    unsigned og[HID2];
#pragma unroll
    for (int i = 0; i < HID2; i++) og[i] = pk2bf(acc[2 * i] * dv, acc[2 * i + 1] * dv);
    uint4* o4 = (uint4*)(g1 + (size_t)node * HID2);
#pragma unroll
    for (int i = 0; i < 4; i++)
        o4[i] = make_uint4(og[4 * i], og[4 * i + 1], og[4 * i + 2], og[4 * i + 3]);
}

// ---------------------------------------------------------------- gather (bf16 rows), optional BN-fuse
template<bool OUT_BF16, bool FUSE_BN>
__global__ __launch_bounds__(256) void ge_gather(const unsigned* __restrict__ g,
                                                 const unsigned* __restrict__ rowst,
                                                 const unsigned* __restrict__ deg,
                                                 const unsigned* __restrict__ col,
                                                 const float* __restrict__ dinv,
                                                 const float* __restrict__ bias,
                                                 unsigned* __restrict__ outb,
                                                 float* __restrict__ outf,
                                                 float* __restrict__ bnsum,
                                                 float* __restrict__ bnsq, int n) {
    int t = threadIdx.x;
    int idx = blockIdx.x * 256 + t;
    int node = idx >> 4, cp = idx & 15;
    float h0 = 0.f, h1v = 0.f;
    if (node < n) {
        unsigned self = g[(size_t)node * HID2 + cp];
        float a0 = bflo(self), a1 = bfhi(self);
        unsigned st = rowst[node], len = deg[node];
        unsigned j = 0;
        for (; j + 4 <= len; j += 4) {
            unsigned c0 = col[st + j + 0];
            unsigned c1 = col[st + j + 1];
            unsigned c2 = col[st + j + 2];
            unsigned c3 = col[st + j + 3];
            unsigned u0 = g[(size_t)c0 * HID2 + cp];
            unsigned u1 = g[(size_t)c1 * HID2 + cp];
            unsigned u2 = g[(size_t)c2 * HID2 + cp];
            unsigned u3 = g[(size_t)c3 * HID2 + cp];
            a0 += (bflo(u0) + bflo(u1)) + (bflo(u2) + bflo(u3));
            a1 += (bfhi(u0) + bfhi(u1)) + (bfhi(u2) + bfhi(u3));
        }
        for (; j < len; j++) {
            unsigned u = g[(size_t)col[st + j] * HID2 + cp];
            a0 += bflo(u); a1 += bfhi(u);
        }
        float dv = dinv[node];
        float2 bb = ((const float2*)bias)[cp];
        h0 = fmaf(dv, a0, bb.x);
        h1v = fmaf(dv, a1, bb.y);
        if (OUT_BF16) {
            outb[(size_t)node * HID2 + cp] = pk2bf(h0, h1v);
        } else {
            float2 o; o.x = h0; o.y = h1v;
            ((float2*)outf)[(size_t)node * HID2 + cp] = o;
        }
    }
    if (FUSE_BN) {
        __shared__ float4 red[256];
        red[t] = make_float4(h0, h0 * h0, h1v, h1v * h1v);
        __syncthreads();
        for (int off = 128; off >= 16; off >>= 1) {
            if (t < off) {
                float4 a = red[t], b = red[t + off];
                red[t] = make_float4(a.x + b.x, a.y + b.y, a.z + b.z, a.w + b.w);
            }
            __syncthreads();
        }
        if (t < 16) {
            float4 v = red[t];
            int p = blockIdx.x & (BNP - 1);
            atomicAdd(&bnsum[p * HID + 2 * t + 0], v.x);
            atomicAdd(&bnsq [p * HID + 2 * t + 0], v.y);
            atomicAdd(&bnsum[p * HID + 2 * t + 1], v.z);
            atomicAdd(&bnsq [p * HID + 2 * t + 1], v.w);
        }
    }
}

// ---------------------------------------------------------------- BN finalize -> affine a,b
__global__ void ge_bnfinal(const float* __restrict__ bnsum, const float* __restrict__ bnsq,
                           const float* __restrict__ gamma, const float* __restrict__ beta,
                           float* __restrict__ ab, int n) {
    int c = threadIdx.x;
    if (c >= HID) return;
    float s = 0.f, q = 0.f;
    for (int p = 0; p < BNP; p++) { s += bnsum[p * HID + c]; q += bnsq[p * HID + c]; }
    float inv_n = 1.f / (float)n;
    float mean = s * inv_n;
    float var = fmaxf(q * inv_n - mean * mean, 0.f);
    float iv = rsqrtf(var + BN_EPS);
    float a = gamma[c] * iv;
    ab[c] = a;
    ab[HID + c] = beta[c] - mean * a;
}

// ---------------------------------------------------------------- g2 = bf16((relu(a*h1+b) @ W2) * dinv)
__global__ __launch_bounds__(256) void ge_gemm2(const unsigned* __restrict__ h1,
                                                const float* __restrict__ W2,
                                                const float* __restrict__ ab,
                                                const float* __restrict__ dinv,
                                                unsigned* __restrict__ g2, int n) {
    int node = blockIdx.x * blockDim.x + threadIdx.x;
    if (node >= n) return;
    float p[HID];
    const uint4* hr = (const uint4*)(h1 + (size_t)node * HID2);
#pragma unroll
    for (int i4 = 0; i4 < 4; i4++) {
        uint4 u4 = hr[i4];
        const unsigned* u = &u4.x;
#pragma unroll
        for (int j = 0; j < 4; j++) {
            int k0 = (i4 * 4 + j) * 2, k1 = k0 + 1;
            p[k0] = fmaxf(fmaf(ab[k0], bflo(u[j]), ab[HID + k0]), 0.f);
            p[k1] = fmaxf(fmaf(ab[k1], bfhi(u[j]), ab[HID + k1]), 0.f);
        }
    }
    float acc[HID];
#pragma unroll
    for (int c = 0; c < HID; c++) acc[c] = 0.f;
#pragma unroll
    for (int k = 0; k < HID; k++) {
        float pk = p[k];
        const float* w = W2 + (size_t)k * HID;
#pragma unroll
        for (int c = 0; c < HID; c++) acc[c] = fmaf(pk, w[c], acc[c]);
    }
    float dv = dinv[node];
    unsigned og[HID2];
#pragma unroll
    for (int i = 0; i < HID2; i++) og[i] = pk2bf(acc[2 * i] * dv, acc[2 * i + 1] * dv);
    uint4* o4 = (uint4*)(g2 + (size_t)node * HID2);
#pragma unroll
    for (int i = 0; i < 4; i++)
        o4[i] = make_uint4(og[4 * i], og[4 * i + 1], og[4 * i + 2], og[4 * i + 3]);
}

// ================================================================ launch
extern "C" void kernel_launch(void* const* d_in, const int* in_sizes, int n_in,
                              void* d_out, int out_size, void* d_ws, size_t ws_size,
                              hipStream_t stream) {
    const float* x     = (const float*)d_in[0];
    const int*   ei    = (const int*)d_in[1];
    const float* W1    = (const float*)d_in[2];
    const float* b1    = (const float*)d_in[3];
    const float* gamma = (const float*)d_in[4];
    const float* beta  = (const float*)d_in[5];
    const float* W2    = (const float*)d_in[6];
    const float* b2    = (const float*)d_in[7];
    float* outp = (float*)d_out;

    const int n = in_sizes[0] / INDIM;        // 100000
    const int E = in_sizes[1] / 2;            // 1600000
    const int nb = (n + 255) >> 8;            // 391 buckets

    // ---- workspace carve-up (256B aligned) ----
    char* w = (char*)d_ws;
    size_t off = 0;
    auto nxt = [&](size_t b) -> void* {
        void* p = w + off;
        off += (b + 255) & ~(size_t)255;
        return p;
    };
    unsigned* bcnt    = (unsigned*)nxt(MAXB * 4);
    float*    bnsum   = (float*)nxt(BNP * HID * 4);
    float*    bnsq    = (float*)nxt(BNP * HID * 4);
    size_t zero_end = off;                    // everything above starts at 0
    unsigned* bstart  = (unsigned*)nxt((MAXB + 1) * 4);
    unsigned* bwptr   = (unsigned*)nxt(MAXB * 4);
    unsigned* deg     = (unsigned*)nxt((size_t)n * 4);
    unsigned* rowst   = (unsigned*)nxt((size_t)n * 4);
    float*    dinv    = (float*)nxt((size_t)n * 4);
    float*    ab      = (float*)nxt(2 * HID * 4);
    unsigned* colx    = (unsigned*)nxt((size_t)E * 4);
    unsigned* g1      = (unsigned*)nxt((size_t)n * HID2 * 4);   // bf16x2 packed
    unsigned* h1      = (unsigned*)nxt((size_t)n * HID2 * 4);   // bf16x2 packed
    unsigned* g2      = g1;                   // g1 dead after first gather
    uint2*    ebuf    = (uint2*)d_out;        // E*8B == out bytes; dead before last gather

    hipMemsetAsync(d_ws, 0, zero_end, stream);

    ge_bhist<<<512, 256, 0, stream>>>(ei, bcnt, E, nb);
    ge_bscan<<<1, MAXB, 0, stream>>>(bcnt, bstart, bwptr, nb, E);
    ge_bpart<<<(E + PCHUNK - 1) / PCHUNK, 256, 0, stream>>>(ei, bwptr, ebuf, E, nb);
    ge_bcsr<<<nb, 256, 0, stream>>>(ebuf, bstart, rowst, deg, dinv, colx, n);

    ge_gemm1<<<(n + 255) / 256, 256, 0, stream>>>(x, W1, dinv, g1, n);

    int gbl = ((n * HID2) + 255) / 256;
    ge_gather<true, true><<<gbl, 256, 0, stream>>>(g1, rowst, deg, colx, dinv, b1,
                                                   h1, nullptr, bnsum, bnsq, n);
    ge_bnfinal<<<1, 64, 0, stream>>>(bnsum, bnsq, gamma, beta, ab, n);

    ge_gemm2<<<(n + 255) / 256, 256, 0, stream>>>(h1, W2, ab, dinv, g2, n);

    ge_gather<false, false><<<gbl, 256, 0, stream>>>(g2, rowst, deg, colx, dinv, b2,
                                                     nullptr, outp, nullptr, nullptr, n);
}